// Round 1
// baseline (1199.529 us; speedup 1.0000x reference)
//
#include <hip/hip_runtime.h>

#define NUSERS 100000
#define NITEMS 50000
#define NNODES (NUSERS + NITEMS)
#define DIM 64
#define NEDGE 2000000

// ---------------------------------------------------------------------------
// init: buf0 = acc = concat(emb_users, emb_items); also write the two
// pass-through output copies (emb_users at out+NUSERS*DIM, emb_items at
// out+2*NUSERS*DIM+NITEMS*DIM). float4 per thread.
// ---------------------------------------------------------------------------
__global__ void init_kernel(const float* __restrict__ eu, const float* __restrict__ eit,
                            float* __restrict__ buf0, float* __restrict__ acc,
                            float* __restrict__ out) {
    long i = (long)blockIdx.x * blockDim.x + threadIdx.x;      // float4 index
    const long total = (long)NNODES * DIM / 4;
    if (i >= total) return;
    const long ue = (long)NUSERS * DIM / 4;
    float4 v;
    if (i < ue) {
        v = ((const float4*)eu)[i];
        ((float4*)(out + (long)NUSERS * DIM))[i] = v;                       // users copy
    } else {
        long j = i - ue;
        v = ((const float4*)eit)[j];
        ((float4*)(out + (long)2 * NUSERS * DIM + (long)NITEMS * DIM))[j] = v; // items copy
    }
    ((float4*)buf0)[i] = v;
    ((float4*)acc)[i] = v;
}

// ---------------------------------------------------------------------------
// scatter: one wave per edge, lane = dim. Gather emb[src] (coalesced 256B),
// atomicAdd into dst row (coalesced 256B, 64 distinct addrs -> no conflict).
// ---------------------------------------------------------------------------
__global__ void scatter_kernel(const int* __restrict__ eidx, const float* __restrict__ ew,
                               const float* __restrict__ src_emb, float* __restrict__ dst_emb) {
    int lane = threadIdx.x & 63;
    int wave = (int)((blockIdx.x * blockDim.x + threadIdx.x) >> 6);
    int nw   = (int)((gridDim.x * (long)blockDim.x) >> 6);
    for (int e = wave; e < NEDGE; e += nw) {
        int s = eidx[e];             // edge_index[0][e]
        int d = eidx[NEDGE + e];     // edge_index[1][e]
        float w = ew[e];
        float v = w * src_emb[(long)s * DIM + lane];
        atomicAdd(dst_emb + (long)d * DIM + lane, v);
    }
}

// ---------------------------------------------------------------------------
// relu + accumulate (+ optionally zero the other ping-pong buffer for the
// next scatter). float4 per thread.
// ---------------------------------------------------------------------------
__global__ void relu_acc_kernel(float* __restrict__ buf, float* __restrict__ acc,
                                float* __restrict__ zbuf, int do_zero) {
    long i = (long)blockIdx.x * blockDim.x + threadIdx.x;
    const long total = (long)NNODES * DIM / 4;
    if (i >= total) return;
    float4 v = ((float4*)buf)[i];
    v.x = fmaxf(v.x, 0.f); v.y = fmaxf(v.y, 0.f);
    v.z = fmaxf(v.z, 0.f); v.w = fmaxf(v.w, 0.f);
    ((float4*)buf)[i] = v;
    float4 a = ((float4*)acc)[i];
    a.x += v.x; a.y += v.y; a.z += v.z; a.w += v.w;
    ((float4*)acc)[i] = a;
    if (do_zero) ((float4*)zbuf)[i] = make_float4(0.f, 0.f, 0.f, 0.f);
}

// ---------------------------------------------------------------------------
// epilogue: out[i][j] = sum_d (acc[i][d]/3) * W[j][d] + b[j]
// One wave per row; lane j owns output col j. W staged in LDS with stride 65
// (bank = (j+d)%32 -> 2-way aliasing, free). Row broadcast via __shfl.
// ---------------------------------------------------------------------------
__global__ void final_kernel(const float* __restrict__ acc, const float* __restrict__ W,
                             const float* __restrict__ bias, float* __restrict__ out) {
    __shared__ float Ws[64 * 65];
    __shared__ float bs[64];
    int tid = threadIdx.x;
    for (int k = tid; k < 64 * 64; k += 256) Ws[(k >> 6) * 65 + (k & 63)] = W[k];
    if (tid < 64) bs[tid] = bias[tid];
    __syncthreads();
    int lane = tid & 63;
    int wv = tid >> 6;
    for (long i = (long)blockIdx.x * 4 + wv; i < NNODES; i += (long)gridDim.x * 4) {
        float a = acc[i * DIM + lane] * (1.0f / 3.0f);
        float sum = bs[lane];
#pragma unroll
        for (int d = 0; d < 64; ++d) {
            sum = fmaf(__shfl(a, d, 64), Ws[lane * 65 + d], sum);
        }
        long o = (i < NUSERS) ? i * DIM
                              : (long)2 * NUSERS * DIM + (i - NUSERS) * DIM;
        out[o + lane] = sum;
    }
}

extern "C" void kernel_launch(void* const* d_in, const int* in_sizes, int n_in,
                              void* d_out, int out_size, void* d_ws, size_t ws_size,
                              hipStream_t stream) {
    const int*   eidx = (const int*)d_in[0];     // (2, E) int
    const float* ew   = (const float*)d_in[1];   // (E,)
    const float* eu   = (const float*)d_in[2];   // (NUSERS, 64)
    const float* eit  = (const float*)d_in[3];   // (NITEMS, 64)
    const float* W    = (const float*)d_in[4];   // (64, 64)
    const float* bias = (const float*)d_in[5];   // (64,)
    float* out = (float*)d_out;

    const size_t nfeat = (size_t)NNODES * DIM;   // 9.6M floats = 38.4 MB
    float* buf0 = (float*)d_ws;
    float* buf1 = buf0 + nfeat;
    float* acc  = buf1 + nfeat;

    const int tpb = 256;
    const long nv4 = (long)NNODES * DIM / 4;
    const int ewBlocks = (int)((nv4 + tpb - 1) / tpb);   // 9375

    // buf1 must start zeroed (ws is re-poisoned to 0xAA before every launch)
    hipMemsetAsync(buf1, 0, nfeat * sizeof(float), stream);

    init_kernel<<<ewBlocks, tpb, 0, stream>>>(eu, eit, buf0, acc, out);

    // layer 1: buf0 -> buf1, then relu+acc on buf1, zero buf0 for next layer
    scatter_kernel<<<4096, tpb, 0, stream>>>(eidx, ew, buf0, buf1);
    relu_acc_kernel<<<ewBlocks, tpb, 0, stream>>>(buf1, acc, buf0, 1);

    // layer 2: buf1 -> buf0, then relu+acc on buf0
    scatter_kernel<<<4096, tpb, 0, stream>>>(eidx, ew, buf1, buf0);
    relu_acc_kernel<<<ewBlocks, tpb, 0, stream>>>(buf0, acc, (float*)nullptr, 0);

    // epilogue GEMM + scatter into the two "final" output slots
    final_kernel<<<37500, tpb, 0, stream>>>(acc, W, bias, out);
}

// Round 2
// 1096.810 us; speedup vs baseline: 1.0937x; 1.0937x over previous
//
#include <hip/hip_runtime.h>

#define NUSERS 100000
#define NITEMS 50000
#define NNODES (NUSERS + NITEMS)
#define DIM 64
#define NEDGE 2000000
#define SCAN_T 1024

// ---------------------------------------------------------------------------
// init: buf0 = acc = concat(emb_users, emb_items); also write the two
// pass-through output copies. float4 per thread.
// ---------------------------------------------------------------------------
__global__ void init_kernel(const float* __restrict__ eu, const float* __restrict__ eit,
                            float* __restrict__ buf0, float* __restrict__ acc,
                            float* __restrict__ out) {
    long i = (long)blockIdx.x * blockDim.x + threadIdx.x;      // float4 index
    const long total = (long)NNODES * DIM / 4;
    if (i >= total) return;
    const long ue = (long)NUSERS * DIM / 4;
    float4 v;
    if (i < ue) {
        v = ((const float4*)eu)[i];
        ((float4*)(out + (long)NUSERS * DIM))[i] = v;                          // users copy
    } else {
        long j = i - ue;
        v = ((const float4*)eit)[j];
        ((float4*)(out + (long)2 * NUSERS * DIM + (long)NITEMS * DIM))[j] = v; // items copy
    }
    ((float4*)buf0)[i] = v;
    ((float4*)acc)[i] = v;
}

// ---------------------------------------------------------------------------
// CSR build step 1: histogram of dst. counts must be pre-zeroed.
// ---------------------------------------------------------------------------
__global__ void hist_kernel(const int* __restrict__ eidx, int* __restrict__ counts) {
    int e = blockIdx.x * blockDim.x + threadIdx.x;
    if (e < NEDGE) atomicAdd(&counts[eidx[NEDGE + e]], 1);
}

// ---------------------------------------------------------------------------
// CSR build step 2: exclusive scan of counts -> row_start (and cursor copy).
// Single block of 1024 threads; each thread owns a contiguous chunk.
// ---------------------------------------------------------------------------
__global__ void scan_kernel(const int* __restrict__ counts, int* __restrict__ row_start,
                            int* __restrict__ cursor) {
    __shared__ int lds[SCAN_T];
    int t = threadIdx.x;
    const int chunk = (NNODES + SCAN_T - 1) / SCAN_T;          // 147
    int begin = t * chunk;
    int end = begin + chunk; if (end > NNODES) end = NNODES;
    int s = 0;
    for (int i = begin; i < end; ++i) s += counts[i];
    lds[t] = s;
    __syncthreads();
    // Hillis-Steele inclusive scan over 1024 partials
    for (int d = 1; d < SCAN_T; d <<= 1) {
        int v = (t >= d) ? lds[t - d] : 0;
        __syncthreads();
        lds[t] += v;
        __syncthreads();
    }
    int off = lds[t] - s;                                      // exclusive offset
    int run = off;
    for (int i = begin; i < end; ++i) {
        row_start[i] = run;
        cursor[i] = run;
        run += counts[i];
    }
    if (t == SCAN_T - 1) row_start[NNODES] = run;              // == NEDGE
}

// ---------------------------------------------------------------------------
// CSR build step 3: bucket edges by dst.
// ---------------------------------------------------------------------------
__global__ void fill_kernel(const int* __restrict__ eidx, const float* __restrict__ ew,
                            int* __restrict__ cursor, int* __restrict__ src_sorted,
                            float* __restrict__ w_sorted) {
    int e = blockIdx.x * blockDim.x + threadIdx.x;
    if (e >= NEDGE) return;
    int d = eidx[NEDGE + e];
    int pos = atomicAdd(&cursor[d], 1);
    src_sorted[pos] = eidx[e];
    w_sorted[pos] = ew[e];
}

// ---------------------------------------------------------------------------
// pull: one wave per dst node, lane = dim. No atomics; fused ReLU + acc.
// 2-way manual unroll for gather-latency ILP.
// ---------------------------------------------------------------------------
__global__ void pull_kernel(const int* __restrict__ row_start, const int* __restrict__ src_sorted,
                            const float* __restrict__ w_sorted, const float* __restrict__ in_emb,
                            float* __restrict__ out_emb, float* __restrict__ acc) {
    int lane = threadIdx.x & 63;
    int n = (int)((blockIdx.x * (long)blockDim.x + threadIdx.x) >> 6);  // node = wave id
    if (n >= NNODES) return;
    int b = row_start[n];
    int e2 = row_start[n + 1];
    float s = 0.f;
    int i = b;
    for (; i + 1 < e2; i += 2) {
        int s0 = src_sorted[i], s1 = src_sorted[i + 1];
        float w0 = w_sorted[i], w1 = w_sorted[i + 1];
        float v0 = in_emb[(long)s0 * DIM + lane];
        float v1 = in_emb[(long)s1 * DIM + lane];
        s = fmaf(w0, v0, s);
        s = fmaf(w1, v1, s);
    }
    if (i < e2) {
        int s0 = src_sorted[i];
        float w0 = w_sorted[i];
        s = fmaf(w0, in_emb[(long)s0 * DIM + lane], s);
    }
    float r = fmaxf(s, 0.f);
    long o = (long)n * DIM + lane;
    out_emb[o] = r;
    acc[o] += r;
}

// ---------------------------------------------------------------------------
// epilogue: out[i][j] = sum_d (acc[i][d]/3) * W[j][d] + b[j]
// One wave per row; lane j owns output col j. W in LDS, stride 65.
// ---------------------------------------------------------------------------
__global__ void final_kernel(const float* __restrict__ acc, const float* __restrict__ W,
                             const float* __restrict__ bias, float* __restrict__ out) {
    __shared__ float Ws[64 * 65];
    __shared__ float bs[64];
    int tid = threadIdx.x;
    for (int k = tid; k < 64 * 64; k += 256) Ws[(k >> 6) * 65 + (k & 63)] = W[k];
    if (tid < 64) bs[tid] = bias[tid];
    __syncthreads();
    int lane = tid & 63;
    int wv = tid >> 6;
    for (long i = (long)blockIdx.x * 4 + wv; i < NNODES; i += (long)gridDim.x * 4) {
        float a = acc[i * DIM + lane] * (1.0f / 3.0f);
        float sum = bs[lane];
#pragma unroll
        for (int d = 0; d < 64; ++d) {
            sum = fmaf(__shfl(a, d, 64), Ws[lane * 65 + d], sum);
        }
        long o = (i < NUSERS) ? i * DIM
                              : (long)2 * NUSERS * DIM + (i - NUSERS) * DIM;
        out[o + lane] = sum;
    }
}

extern "C" void kernel_launch(void* const* d_in, const int* in_sizes, int n_in,
                              void* d_out, int out_size, void* d_ws, size_t ws_size,
                              hipStream_t stream) {
    const int*   eidx = (const int*)d_in[0];     // (2, E) int
    const float* ew   = (const float*)d_in[1];   // (E,)
    const float* eu   = (const float*)d_in[2];   // (NUSERS, 64)
    const float* eit  = (const float*)d_in[3];   // (NITEMS, 64)
    const float* W    = (const float*)d_in[4];   // (64, 64)
    const float* bias = (const float*)d_in[5];   // (64,)
    float* out = (float*)d_out;

    const size_t nfeat = (size_t)NNODES * DIM;   // 9.6M floats
    float* buf0 = (float*)d_ws;
    float* buf1 = buf0 + nfeat;
    float* acc  = buf1 + nfeat;
    int*   counts     = (int*)(acc + nfeat);
    int*   row_start  = counts + NNODES;         // NNODES+1 entries
    int*   cursor     = row_start + NNODES + 1;
    int*   src_sorted = cursor + NNODES;
    float* w_sorted   = (float*)(src_sorted + NEDGE);
    // total ws use: 3*38.4MB + ~1.8MB + 16MB  ≈ 133 MB

    const int tpb = 256;
    const long nv4 = (long)NNODES * DIM / 4;
    const int ewBlocks = (int)((nv4 + tpb - 1) / tpb);          // 9375
    const int edgeBlocks = (NEDGE + tpb - 1) / tpb;             // 7813
    const int nodeWaveBlocks = (NNODES * 64 + tpb - 1) / tpb;   // 37500

    hipMemsetAsync(counts, 0, NNODES * sizeof(int), stream);

    init_kernel<<<ewBlocks, tpb, 0, stream>>>(eu, eit, buf0, acc, out);

    // Build CSR by dst (once; reused by both layers)
    hist_kernel<<<edgeBlocks, tpb, 0, stream>>>(eidx, counts);
    scan_kernel<<<1, SCAN_T, 0, stream>>>(counts, row_start, cursor);
    fill_kernel<<<edgeBlocks, tpb, 0, stream>>>(eidx, ew, cursor, src_sorted, w_sorted);

    // layer 1: buf0 -> buf1 (fused relu + acc)
    pull_kernel<<<nodeWaveBlocks, tpb, 0, stream>>>(row_start, src_sorted, w_sorted, buf0, buf1, acc);
    // layer 2: buf1 -> buf0
    pull_kernel<<<nodeWaveBlocks, tpb, 0, stream>>>(row_start, src_sorted, w_sorted, buf1, buf0, acc);

    // epilogue GEMM + writes into the two "final" output slots
    final_kernel<<<37500, tpb, 0, stream>>>(acc, W, bias, out);
}

// Round 3
// 780.608 us; speedup vs baseline: 1.5367x; 1.4051x over previous
//
#include <hip/hip_runtime.h>

#define NUSERS 100000
#define NITEMS 50000
#define NNODES (NUSERS + NITEMS)
#define DIM 64
#define NEDGE 2000000
#define NI4 (NNODES / 4)            // 37500 int4 count-groups
#define SCAN_B ((NI4 + 255) / 256)  // 147 blocks

// ---------------------------------------------------------------------------
// init: buf0 = acc = concat(emb_users, emb_items); also write the two
// pass-through output copies. float4 per thread.
// ---------------------------------------------------------------------------
__global__ void init_kernel(const float* __restrict__ eu, const float* __restrict__ eit,
                            float* __restrict__ buf0, float* __restrict__ acc,
                            float* __restrict__ out) {
    long i = (long)blockIdx.x * blockDim.x + threadIdx.x;      // float4 index
    const long total = (long)NNODES * DIM / 4;
    if (i >= total) return;
    const long ue = (long)NUSERS * DIM / 4;
    float4 v;
    if (i < ue) {
        v = ((const float4*)eu)[i];
        ((float4*)(out + (long)NUSERS * DIM))[i] = v;                          // users copy
    } else {
        long j = i - ue;
        v = ((const float4*)eit)[j];
        ((float4*)(out + (long)2 * NUSERS * DIM + (long)NITEMS * DIM))[j] = v; // items copy
    }
    ((float4*)buf0)[i] = v;
    ((float4*)acc)[i] = v;
}

// ---------------------------------------------------------------------------
// CSR build step 1: histogram of dst. counts must be pre-zeroed.
// ---------------------------------------------------------------------------
__global__ void hist_kernel(const int* __restrict__ eidx, int* __restrict__ counts) {
    int e = blockIdx.x * blockDim.x + threadIdx.x;
    if (e < NEDGE) atomicAdd(&counts[eidx[NEDGE + e]], 1);
}

// ---------------------------------------------------------------------------
// CSR build step 2a: per-block sums (1024 counts per block via int4).
// ---------------------------------------------------------------------------
__global__ void blk_sum_kernel(const int* __restrict__ counts, int* __restrict__ blk_sums) {
    __shared__ int lds[256];
    int t = threadIdx.x;
    int i4 = blockIdx.x * 256 + t;
    int s = 0;
    if (i4 < NI4) {
        int4 c = ((const int4*)counts)[i4];
        s = c.x + c.y + c.z + c.w;
    }
    lds[t] = s;
    __syncthreads();
    for (int d = 128; d > 0; d >>= 1) {
        if (t < d) lds[t] += lds[t + d];
        __syncthreads();
    }
    if (t == 0) blk_sums[blockIdx.x] = lds[0];
}

// ---------------------------------------------------------------------------
// CSR build step 2b: exclusive scan of the SCAN_B block sums (single block).
// ---------------------------------------------------------------------------
__global__ void blk_scan_kernel(const int* __restrict__ blk_sums, int* __restrict__ blk_off) {
    __shared__ int lds[256];
    int t = threadIdx.x;
    int v = (t < SCAN_B) ? blk_sums[t] : 0;
    lds[t] = v;
    __syncthreads();
    for (int d = 1; d < 256; d <<= 1) {
        int u = (t >= d) ? lds[t - d] : 0;
        __syncthreads();
        lds[t] += u;
        __syncthreads();
    }
    if (t < SCAN_B) blk_off[t] = lds[t] - v;   // exclusive
}

// ---------------------------------------------------------------------------
// CSR build step 2c: local exclusive scan + block offset -> row_start, cursor.
// ---------------------------------------------------------------------------
__global__ void scan_apply_kernel(const int* __restrict__ counts, const int* __restrict__ blk_off,
                                  int* __restrict__ row_start, int* __restrict__ cursor) {
    __shared__ int lds[256];
    int t = threadIdx.x;
    int i4 = blockIdx.x * 256 + t;
    int4 c = make_int4(0, 0, 0, 0);
    if (i4 < NI4) c = ((const int4*)counts)[i4];
    int tsum = c.x + c.y + c.z + c.w;
    lds[t] = tsum;
    __syncthreads();
    for (int d = 1; d < 256; d <<= 1) {
        int u = (t >= d) ? lds[t - d] : 0;
        __syncthreads();
        lds[t] += u;
        __syncthreads();
    }
    if (i4 < NI4) {
        int base = blk_off[blockIdx.x] + lds[t] - tsum;   // exclusive across chunk
        int4 r;
        r.x = base;
        r.y = base + c.x;
        r.z = r.y + c.y;
        r.w = r.z + c.z;
        ((int4*)row_start)[i4] = r;
        ((int4*)cursor)[i4] = r;
    }
    if (blockIdx.x == 0 && t == 0) row_start[NNODES] = NEDGE;
}

// ---------------------------------------------------------------------------
// CSR build step 3: bucket edges by dst.
// ---------------------------------------------------------------------------
__global__ void fill_kernel(const int* __restrict__ eidx, const float* __restrict__ ew,
                            int* __restrict__ cursor, int* __restrict__ src_sorted,
                            float* __restrict__ w_sorted) {
    int e = blockIdx.x * blockDim.x + threadIdx.x;
    if (e >= NEDGE) return;
    int d = eidx[NEDGE + e];
    int pos = atomicAdd(&cursor[d], 1);
    src_sorted[pos] = eidx[e];
    w_sorted[pos] = ew[e];
}

// ---------------------------------------------------------------------------
// pull: one wave per dst node, lane = dim. No atomics; fused ReLU + acc.
// ---------------------------------------------------------------------------
__global__ void pull_kernel(const int* __restrict__ row_start, const int* __restrict__ src_sorted,
                            const float* __restrict__ w_sorted, const float* __restrict__ in_emb,
                            float* __restrict__ out_emb, float* __restrict__ acc) {
    int lane = threadIdx.x & 63;
    int n = (int)((blockIdx.x * (long)blockDim.x + threadIdx.x) >> 6);  // node = wave id
    if (n >= NNODES) return;
    int b = row_start[n];
    int e2 = row_start[n + 1];
    float s = 0.f;
    int i = b;
    for (; i + 1 < e2; i += 2) {
        int s0 = src_sorted[i], s1 = src_sorted[i + 1];
        float w0 = w_sorted[i], w1 = w_sorted[i + 1];
        float v0 = in_emb[(long)s0 * DIM + lane];
        float v1 = in_emb[(long)s1 * DIM + lane];
        s = fmaf(w0, v0, s);
        s = fmaf(w1, v1, s);
    }
    if (i < e2) {
        int s0 = src_sorted[i];
        float w0 = w_sorted[i];
        s = fmaf(w0, in_emb[(long)s0 * DIM + lane], s);
    }
    float r = fmaxf(s, 0.f);
    long o = (long)n * DIM + lane;
    out_emb[o] = r;
    acc[o] += r;
}

// ---------------------------------------------------------------------------
// epilogue: out[i][j] = sum_d (acc[i][d]/3) * W[j][d] + b[j]
// One wave per row; lane j owns output col j. W in LDS, stride 65.
// ---------------------------------------------------------------------------
__global__ void final_kernel(const float* __restrict__ acc, const float* __restrict__ W,
                             const float* __restrict__ bias, float* __restrict__ out) {
    __shared__ float Ws[64 * 65];
    __shared__ float bs[64];
    int tid = threadIdx.x;
    for (int k = tid; k < 64 * 64; k += 256) Ws[(k >> 6) * 65 + (k & 63)] = W[k];
    if (tid < 64) bs[tid] = bias[tid];
    __syncthreads();
    int lane = tid & 63;
    int wv = tid >> 6;
    for (long i = (long)blockIdx.x * 4 + wv; i < NNODES; i += (long)gridDim.x * 4) {
        float a = acc[i * DIM + lane] * (1.0f / 3.0f);
        float sum = bs[lane];
#pragma unroll
        for (int d = 0; d < 64; ++d) {
            sum = fmaf(__shfl(a, d, 64), Ws[lane * 65 + d], sum);
        }
        long o = (i < NUSERS) ? i * DIM
                              : (long)2 * NUSERS * DIM + (i - NUSERS) * DIM;
        out[o + lane] = sum;
    }
}

extern "C" void kernel_launch(void* const* d_in, const int* in_sizes, int n_in,
                              void* d_out, int out_size, void* d_ws, size_t ws_size,
                              hipStream_t stream) {
    const int*   eidx = (const int*)d_in[0];     // (2, E) int
    const float* ew   = (const float*)d_in[1];   // (E,)
    const float* eu   = (const float*)d_in[2];   // (NUSERS, 64)
    const float* eit  = (const float*)d_in[3];   // (NITEMS, 64)
    const float* W    = (const float*)d_in[4];   // (64, 64)
    const float* bias = (const float*)d_in[5];   // (64,)
    float* out = (float*)d_out;

    const size_t nfeat = (size_t)NNODES * DIM;   // 9.6M floats
    float* buf0 = (float*)d_ws;
    float* buf1 = buf0 + nfeat;
    float* acc  = buf1 + nfeat;
    int*   counts     = (int*)(acc + nfeat);
    int*   row_start  = counts + NNODES;         // NNODES+1 entries
    int*   cursor     = row_start + NNODES + 1;
    int*   blk_sums   = cursor + NNODES;
    int*   blk_off    = blk_sums + SCAN_B;
    int*   src_sorted = blk_off + SCAN_B + 2;    // keep int4 alignment slack
    float* w_sorted   = (float*)(src_sorted + NEDGE);

    const int tpb = 256;
    const long nv4 = (long)NNODES * DIM / 4;
    const int ewBlocks = (int)((nv4 + tpb - 1) / tpb);          // 9375
    const int edgeBlocks = (NEDGE + tpb - 1) / tpb;             // 7813
    const int nodeWaveBlocks = (NNODES * 64 + tpb - 1) / tpb;   // 37500

    hipMemsetAsync(counts, 0, NNODES * sizeof(int), stream);

    init_kernel<<<ewBlocks, tpb, 0, stream>>>(eu, eit, buf0, acc, out);

    // Build CSR by dst (parallel 3-phase scan)
    hist_kernel<<<edgeBlocks, tpb, 0, stream>>>(eidx, counts);
    blk_sum_kernel<<<SCAN_B, 256, 0, stream>>>(counts, blk_sums);
    blk_scan_kernel<<<1, 256, 0, stream>>>(blk_sums, blk_off);
    scan_apply_kernel<<<SCAN_B, 256, 0, stream>>>(counts, blk_off, row_start, cursor);
    fill_kernel<<<edgeBlocks, tpb, 0, stream>>>(eidx, ew, cursor, src_sorted, w_sorted);

    // layer 1: buf0 -> buf1 (fused relu + acc)
    pull_kernel<<<nodeWaveBlocks, tpb, 0, stream>>>(row_start, src_sorted, w_sorted, buf0, buf1, acc);
    // layer 2: buf1 -> buf0
    pull_kernel<<<nodeWaveBlocks, tpb, 0, stream>>>(row_start, src_sorted, w_sorted, buf1, buf0, acc);

    // epilogue GEMM + writes into the two "final" output slots
    final_kernel<<<37500, tpb, 0, stream>>>(acc, W, bias, out);
}